// Round 12
// baseline (2319.742 us; speedup 1.0000x reference)
//
#include <hip/hip_runtime.h>
#include <math.h>

#define T_STEPS 8
#define NN 50000
#define EE 800000
#define TN (T_STEPS*NN)   // 400000
#define TE (T_STEPS*EE)   // 6400000
#define GX 391            // (NN+127)/128
#define CPB 12500         // count blocks at 512 thr (TE/512)
#define FPB 25000         // fill blocks at 256 thr (TE/256)

typedef unsigned int uint;
typedef unsigned short ushort;
typedef unsigned long long u64;
typedef __attribute__((ext_vector_type(8))) short short8;
typedef __attribute__((ext_vector_type(4))) float f32x4;

__device__ __forceinline__ float sigf(float x){ return 1.0f/(1.0f+expf(-x)); }
__device__ __forceinline__ ushort f2b(float f){
  uint x = __float_as_uint(f);
  uint r = (x + 0x7fffu + ((x>>16)&1u)) >> 16;
  return (ushort)r;
}
__device__ __forceinline__ float b2f(ushort u){ return __uint_as_float(((uint)u)<<16); }

__device__ __forceinline__ void gload16(const ushort* g, ushort* l){
  __builtin_amdgcn_global_load_lds(
      (const __attribute__((address_space(1))) void*)g,
      (__attribute__((address_space(3))) void*)l, 16, 0, 0);
}

// stage ROWS x 64 bf16 tile into LDS (pre-swizzled source, linear dest), 256 thr
template<int ROWS>
__device__ __forceinline__ void stage_tile(const ushort* base, int ld, int rowclamp,
                                           ushort* lds, int lane, int wid){
  constexpr int ITERS = ROWS/32;
#pragma unroll
  for (int i=0;i<ITERS;i++){
    int lin = i*256 + wid*64 + lane;
    int row = lin>>3, s = lin&7;
    int gr = row; if (gr > rowclamp) gr = rowclamp;
    const ushort* gp = base + (size_t)gr*ld + ((s ^ (row&7))<<3);
    gload16(gp, lds + (size_t)(i*256 + wid*64)*8);
  }
}

// same, for 512-thread blocks
template<int ROWS>
__device__ __forceinline__ void stage512(const ushort* base, int ld, int rowclamp,
                                         ushort* lds, int tid){
  constexpr int ITERS = ROWS/64;
#pragma unroll
  for (int i=0;i<ITERS;i++){
    int lin = i*512 + tid;
    int row = lin>>3, s = lin&7;
    int gr = row; if (gr > rowclamp) gr = rowclamp;
    const ushort* gp = base + (size_t)gr*ld + ((s ^ (row&7))<<3);
    gload16(gp, lds + (size_t)lin*8);
  }
}

__device__ __forceinline__ short8 fragld(const ushort* lds, int R, int kk, int lane){
  int slot = (kk*4 + (lane>>4)) ^ (R&7);
  return *(const short8*)&lds[R*64 + slot*8];
}

struct Seg { const ushort* p; int ld; long ts; int w; };

// ================= generic bf16 MFMA GEMM (128x128 tile, 3-seg A, batched t) ======
__global__ __launch_bounds__(256,2) void gemm_bf(
    Seg s0, Seg s1, Seg s2,
    const ushort* __restrict__ W, int K2, long Wts,
    const float* __restrict__ bias, int act,
    const ushort* __restrict__ addp, int ldad, long adts,
    float* __restrict__ C32, int ldc, long c32ts,
    ushort* __restrict__ C16, int ldb, long c16ts,
    int Nrow, int NOvalid)
{
  __shared__ __align__(16) ushort As[8192];
  __shared__ __align__(16) ushort Bs[8192];
  const int t    = blockIdx.z;
  const int tid  = threadIdx.x;
  const int lane = tid & 63;
  const int wid  = __builtin_amdgcn_readfirstlane(tid >> 6);
  const int brow = blockIdx.x*128;
  const int bcol = blockIdx.y*128;
  const int wr = wid>>1, wc = wid&1;

  f32x4 acc[4][4];
#pragma unroll
  for(int m=0;m<4;m++)
#pragma unroll
    for(int n=0;n<4;n++) acc[m][n] = (f32x4){0.f,0.f,0.f,0.f};

  const int nk = K2 >> 6;
  for (int kt=0; kt<nk; ++kt){
    int col0 = kt*64;
    const ushort* ab; int ald;
    if (col0 < s0.w){ ab = s0.p + (size_t)t*s0.ts + col0; ald = s0.ld; }
    else if (col0 < s0.w + s1.w){ ab = s1.p + (size_t)t*s1.ts + (col0 - s0.w); ald = s1.ld; }
    else { ab = s2.p + (size_t)t*s2.ts + (col0 - s0.w - s1.w); ald = s2.ld; }
    stage_tile<128>(ab + (size_t)brow*ald, ald, Nrow-1-brow, As, lane, wid);
    stage_tile<128>(W + (size_t)t*Wts + (size_t)bcol*K2 + col0, K2, 1<<30, Bs, lane, wid);
    __syncthreads();
#pragma unroll
    for (int kk=0;kk<2;kk++){
      short8 a[4], b[4];
#pragma unroll
      for (int m=0;m<4;m++) a[m] = fragld(As, wr*64 + m*16 + (lane&15), kk, lane);
#pragma unroll
      for (int n=0;n<4;n++) b[n] = fragld(Bs, wc*64 + n*16 + (lane&15), kk, lane);
#pragma unroll
      for (int m=0;m<4;m++)
#pragma unroll
        for (int n=0;n<4;n++)
          acc[m][n] = __builtin_amdgcn_mfma_f32_16x16x32_bf16(a[m], b[n], acc[m][n], 0,0,0);
    }
    __syncthreads();
  }
  const int rbase = brow + wr*64 + (lane>>4)*4;
  const int cbase = bcol + wc*64 + (lane&15);
#pragma unroll
  for (int m=0;m<4;m++){
#pragma unroll
    for (int q=0;q<4;q++){
      int r = rbase + m*16 + q;
      if (r >= Nrow) continue;
#pragma unroll
      for (int n=0;n<4;n++){
        int c = cbase + n*16;
        if (c >= NOvalid) continue;
        float v = acc[m][n][q];
        if (addp) v += b2f(addp[(size_t)t*adts + (size_t)r*ldad + c]);
        if (bias) v += bias[c];
        if (act==1) v = fmaxf(v, 0.f);
        if (C32) C32[(size_t)t*c32ts + (size_t)r*ldc + c] = v;
        if (C16) C16[(size_t)t*c16ts + (size_t)r*ldb + c] = f2b(v);
      }
    }
  }
}

// ====== FUSED: count (blocks 0..CPB-1) ∥ phi GEMM (rest), 512 threads ============
// count: u32 atomic packs count<<24 | sum_q18 (deg max ~40 << 255; sum < 2^24).
// phi: 128x256 tile, fp32 X read + bf16 convert in staging, acc[4][4]/wave.
__global__ __launch_bounds__(512,2) void count_phi_k(
    const int* __restrict__ ei, const float* __restrict__ ewl,
    uint* __restrict__ degcnt, ushort* __restrict__ rank,
    const float* __restrict__ A32, const ushort* __restrict__ W,
    const float* __restrict__ bias,
    ushort* __restrict__ C16, long c16ts, int Nrow)
{
  __shared__ __align__(16) ushort As[8192];    // 128 x 64
  __shared__ __align__(16) ushort Bs[16384];   // 256 x 64
  if (blockIdx.x < CPB){
    int idx = blockIdx.x*512 + threadIdx.x;
    if (idx >= TE) return;
    int t = idx / EE;
    int e = idx - t*EE;
    const int* dst = ei + (size_t)t*2*EE + EE;
    int d = dst[e];
    uint v = (1u<<24) | (uint)(sigf(ewl[idx]) * 262144.0f);
    uint old = atomicAdd(&degcnt[t*NN + d], v);
    rank[idx] = (ushort)(old>>24);
    return;
  }
  const int pb   = blockIdx.x - CPB;
  const int t    = pb / GX;
  const int bx   = pb - t*GX;
  const int tid  = threadIdx.x;
  const int lane = tid & 63;
  const int wid  = __builtin_amdgcn_readfirstlane(tid >> 6);
  const int brow = bx*128;
  const int wr = wid>>2, wc = wid&3;           // 2 x 4 wave grid
  const float* At = A32 + (size_t)t*NN*128;

  f32x4 acc[4][4];
#pragma unroll
  for(int m=0;m<4;m++)
#pragma unroll
    for(int n=0;n<4;n++) acc[m][n] = (f32x4){0.f,0.f,0.f,0.f};

  for (int kt=0; kt<2; ++kt){
    int col0 = kt*64;
#pragma unroll
    for (int it=0; it<4; ++it){
      int lin = it*512 + tid;          // float4 unit, 0..2047
      int row = lin>>4, q4 = lin&15;
      int grow = brow + row; if (grow >= Nrow) grow = Nrow-1;
      float4 v = *(const float4*)&At[(size_t)grow*128 + col0 + q4*4];
      int s = q4>>1, half = q4&1;
      uint lo = (uint)f2b(v.x) | ((uint)f2b(v.y)<<16);
      uint hi = (uint)f2b(v.z) | ((uint)f2b(v.w)<<16);
      *(uint2*)&As[row*64 + ((s ^ (row&7))<<3) + half*4] = make_uint2(lo,hi);
    }
    stage512<256>(W + col0, 128, 1<<30, Bs, tid);
    __syncthreads();
#pragma unroll
    for (int kk=0;kk<2;kk++){
      short8 a[4], b[4];
#pragma unroll
      for (int m=0;m<4;m++) a[m] = fragld(As, wr*64 + m*16 + (lane&15), kk, lane);
#pragma unroll
      for (int n=0;n<4;n++) b[n] = fragld(Bs, wc*64 + n*16 + (lane&15), kk, lane);
#pragma unroll
      for (int m=0;m<4;m++)
#pragma unroll
        for (int n=0;n<4;n++)
          acc[m][n] = __builtin_amdgcn_mfma_f32_16x16x32_bf16(a[m], b[n], acc[m][n], 0,0,0);
    }
    __syncthreads();
  }
  const int rbase = brow + wr*64 + (lane>>4)*4;
  const int cbase = wc*64 + (lane&15);
#pragma unroll
  for (int m=0;m<4;m++){
#pragma unroll
    for (int q=0;q<4;q++){
      int r = rbase + m*16 + q;
      if (r >= Nrow) continue;
#pragma unroll
      for (int n=0;n<4;n++){
        int c = cbase + n*16;
        float v = acc[m][n][q] + bias[c];
        v = fmaxf(v, 0.f);
        C16[(size_t)t*c16ts + (size_t)r*256 + c] = f2b(v);
      }
    }
  }
}

// ====== FUSED: fill (blocks 0..FPB-1) ∥ xw GEMM (rest), 256 threads ==============
__global__ __launch_bounds__(256,2) void fill_xw_k(
    const int* __restrict__ ei, const float* __restrict__ ewl,
    const float* __restrict__ dnv, const int* __restrict__ offs,
    const ushort* __restrict__ rank, uint* __restrict__ epack,
    const ushort* __restrict__ phiA, const ushort* __restrict__ gcWt,
    ushort* __restrict__ xwb, int Nrow)
{
  __shared__ __align__(16) ushort As[8192];
  __shared__ __align__(16) ushort Bs[8192];
  if (blockIdx.x < FPB){
    int idx = blockIdx.x*256 + threadIdx.x;
    if (idx >= TE) return;
    int t = idx / EE;
    int e = idx - t*EE;
    const int* srcp = ei + (size_t)t*2*EE;
    const int* dstp = srcp + EE;
    int s=srcp[e], d=dstp[e];
    float nr = dnv[t*NN+s] * sigf(ewl[idx]) * dnv[t*NN+d];
    uint nq = (uint)(nr*65535.f + 0.5f);
    int pos = offs[t*NN+d] + rank[idx];
    epack[pos] = (uint)s | (nq<<16);
    return;
  }
  const int pb   = blockIdx.x - FPB;
  const int t    = pb / GX;
  const int bx   = pb - t*GX;
  const int tid  = threadIdx.x;
  const int lane = tid & 63;
  const int wid  = __builtin_amdgcn_readfirstlane(tid >> 6);
  const int brow = bx*128;
  const int wr = wid>>1, wc = wid&1;
  const ushort* A = phiA + (size_t)t*NN*256;
  const ushort* W = gcWt + (size_t)t*128*256;

  f32x4 acc[4][4];
#pragma unroll
  for(int m=0;m<4;m++)
#pragma unroll
    for(int n=0;n<4;n++) acc[m][n] = (f32x4){0.f,0.f,0.f,0.f};

  for (int kt=0; kt<4; ++kt){
    int col0 = kt*64;
    stage_tile<128>(A + (size_t)brow*256 + col0, 256, Nrow-1-brow, As, lane, wid);
    stage_tile<128>(W + col0, 256, 1<<30, Bs, lane, wid);
    __syncthreads();
#pragma unroll
    for (int kk=0;kk<2;kk++){
      short8 a[4], b[4];
#pragma unroll
      for (int m=0;m<4;m++) a[m] = fragld(As, wr*64 + m*16 + (lane&15), kk, lane);
#pragma unroll
      for (int n=0;n<4;n++) b[n] = fragld(Bs, wc*64 + n*16 + (lane&15), kk, lane);
#pragma unroll
      for (int m=0;m<4;m++)
#pragma unroll
        for (int n=0;n<4;n++)
          acc[m][n] = __builtin_amdgcn_mfma_f32_16x16x32_bf16(a[m], b[n], acc[m][n], 0,0,0);
    }
    __syncthreads();
  }
  const int rbase = brow + wr*64 + (lane>>4)*4;
  const int cbase = wc*64 + (lane&15);
#pragma unroll
  for (int m=0;m<4;m++){
#pragma unroll
    for (int q=0;q<4;q++){
      int r = rbase + m*16 + q;
      if (r >= Nrow) continue;
#pragma unroll
      for (int n=0;n<4;n++){
        int c = cbase + n*16;
        xwb[(size_t)t*NN*128 + (size_t)r*128 + c] = f2b(acc[m][n][q]);
      }
    }
  }
}

// ====== fused GRU GEMM, 512 threads, 128 rows x 256 gate-cols, 2x4 wave grid =====
__global__ __launch_bounds__(512,2) void gemm_gru512(
    Seg s0, Seg s1, Seg s2,
    const ushort* __restrict__ W,                        // Wgru [1024][448]
    const float* __restrict__ bg,                        // [1024]
    const float* __restrict__ hin,                       // fp32 h_t
    float* __restrict__ hout, ushort* __restrict__ hbfo, // hbfo != s2.p (ping-pong!)
    int Nrow)
{
  __shared__ __align__(16) ushort As[8192];    // 128 x 64
  __shared__ __align__(16) ushort Bs[16384];   // 256 x 64
  const int tid  = threadIdx.x;
  const int lane = tid & 63;
  const int wid  = __builtin_amdgcn_readfirstlane(tid >> 6);   // 0..7
  const int brow = blockIdx.x*128;
  const int bcol = blockIdx.y*256;
  const int wr = wid>>2, wc = wid&3;           // 2 x 4 wave grid
  const int K2 = 448;

  f32x4 acc[4][4];
#pragma unroll
  for(int m=0;m<4;m++)
#pragma unroll
    for(int n=0;n<4;n++) acc[m][n] = (f32x4){0.f,0.f,0.f,0.f};

  for (int kt=0; kt<7; ++kt){
    int col0 = kt*64;
    const ushort* ab; int ald;
    if (col0 < s0.w){ ab = s0.p + col0; ald = s0.ld; }
    else if (col0 < s0.w + s1.w){ ab = s1.p + (col0 - s0.w); ald = s1.ld; }
    else { ab = s2.p + (col0 - s0.w - s1.w); ald = s2.ld; }
    stage512<128>(ab + (size_t)brow*ald, ald, Nrow-1-brow, As, tid);
    stage512<256>(W + (size_t)bcol*K2 + col0, K2, 1<<30, Bs, tid);
    __syncthreads();
#pragma unroll
    for (int kk=0;kk<2;kk++){
      short8 a[4], b[4];
#pragma unroll
      for (int m=0;m<4;m++) a[m] = fragld(As, wr*64 + m*16 + (lane&15), kk, lane);
#pragma unroll
      for (int n=0;n<4;n++) b[n] = fragld(Bs, wc*64 + n*16 + (lane&15), kk, lane);
#pragma unroll
      for (int m=0;m<4;m++)
#pragma unroll
        for (int n=0;n<4;n++)
          acc[m][n] = __builtin_amdgcn_mfma_f32_16x16x32_bf16(a[m], b[n], acc[m][n], 0,0,0);
    }
    __syncthreads();
  }
  // c = bcol + wc*64 + n*16 + jj ; G = c>>6 = y*4+wc ; j = G*16+jj ; gate = n
  const int jj = lane&15;
  const int G  = blockIdx.y*4 + wc;
  const int j  = G*16 + jj;
  const int rbase = brow + wr*64 + (lane>>4)*4;
  float bb[4];
#pragma unroll
  for (int n=0;n<4;n++) bb[n] = bg[G*64 + n*16 + jj];
#pragma unroll
  for (int m=0;m<4;m++){
#pragma unroll
    for (int q=0;q<4;q++){
      int r = rbase + m*16 + q;
      if (r >= Nrow) continue;
      float v0 = acc[m][0][q] + bb[0];
      float v1 = acc[m][1][q] + bb[1];
      float v2 = acc[m][2][q] + bb[2];
      float v3 = acc[m][3][q] + bb[3];
      float rg = sigf(v0), ug = sigf(v1);
      float ng = tanhf(v2 + rg*v3);
      float ho = hin[(size_t)r*256 + j];
      float hn = (1.f-ug)*ng + ug*ho;
      hout[(size_t)r*256 + j] = hn;
      hbfo[(size_t)r*256 + j] = f2b(hn);
    }
  }
}

// ================= fused outcome heads (batched over t) ==============
__global__ __launch_bounds__(256,2) void heads_k(
    const ushort* __restrict__ Az, long Ats,             // zbf_all, ld 128
    const ushort* __restrict__ W,                        // wocT [256][128]
    const float* __restrict__ o00b, const float* __restrict__ o10b,
    const float* __restrict__ w01, const float* __restrict__ b01,
    const float* __restrict__ w11, const float* __restrict__ b11,
    float* __restrict__ y0out, long y0ts,
    float* __restrict__ y1out, long y1ts, int Nrow)
{
  __shared__ __align__(16) ushort As[4096];
  __shared__ __align__(16) ushort Bs[16384];
  __shared__ float shy[4][64];
  const int t    = blockIdx.z;
  const int tid  = threadIdx.x;
  const int lane = tid & 63;
  const int wid  = __builtin_amdgcn_readfirstlane(tid >> 6);
  const int brow = blockIdx.x*64;
  const ushort* A = Az + (size_t)t*Ats;

  f32x4 acc[4][4];
#pragma unroll
  for(int m=0;m<4;m++)
#pragma unroll
    for(int n=0;n<4;n++) acc[m][n] = (f32x4){0.f,0.f,0.f,0.f};

  for (int kt=0; kt<2; ++kt){
    stage_tile<64>(A + (size_t)brow*128 + kt*64, 128, Nrow-1-brow, As, lane, wid);
    stage_tile<256>(W + kt*64, 128, 1<<30, Bs, lane, wid);
    __syncthreads();
#pragma unroll
    for (int kk=0;kk<2;kk++){
      short8 a[4], b[4];
#pragma unroll
      for (int m=0;m<4;m++) a[m] = fragld(As, m*16 + (lane&15), kk, lane);
#pragma unroll
      for (int n=0;n<4;n++) b[n] = fragld(Bs, wid*64 + n*16 + (lane&15), kk, lane);
#pragma unroll
      for (int m=0;m<4;m++)
#pragma unroll
        for (int n=0;n<4;n++)
          acc[m][n] = __builtin_amdgcn_mfma_f32_16x16x32_bf16(a[m], b[n], acc[m][n], 0,0,0);
    }
    __syncthreads();
  }
  float bb[4], ww[4];
#pragma unroll
  for (int n=0;n<4;n++){
    int c = wid*64 + n*16 + (lane&15);
    bb[n] = (c<128)? o00b[c] : o10b[c-128];
    ww[n] = (c<128)? w01[c]  : w11[c-128];
  }
#pragma unroll
  for (int m=0;m<4;m++){
#pragma unroll
    for (int q=0;q<4;q++){
      float p = 0.f;
#pragma unroll
      for (int n=0;n<4;n++) p += fmaxf(acc[m][n][q] + bb[n], 0.f) * ww[n];
#pragma unroll
      for (int o=1;o<16;o<<=1) p += __shfl_xor(p, o);
      if ((lane&15)==0) shy[wid][m*16 + (lane>>4)*4 + q] = p;
    }
  }
  __syncthreads();
  if (tid < 64){
    int r = brow + tid;
    if (r < Nrow){
      y0out[(size_t)t*y0ts + r] = shy[0][tid] + shy[1][tid] + b01[0];
      y1out[(size_t)t*y1ts + r] = shy[2][tid] + shy[3][tid] + b11[0];
    }
  }
}

// ================= fused propensity head (batched over t) ==============
__global__ __launch_bounds__(256,2) void ps_k(
    const ushort* __restrict__ Az, long Ats,             // zbf_all, ld 128
    const ushort* __restrict__ W,                        // ps1T [128][128]
    const float* __restrict__ psc, const float* __restrict__ psb,
    const float* __restrict__ W2, const float* __restrict__ b2,
    float* __restrict__ psout, long psts, int Nrow)
{
  __shared__ __align__(16) ushort As[8192];
  __shared__ __align__(16) ushort Bs[8192];
  __shared__ float sh0[2][128];
  __shared__ float sh1[2][128];
  const int t    = blockIdx.z;
  const int tid  = threadIdx.x;
  const int lane = tid & 63;
  const int wid  = __builtin_amdgcn_readfirstlane(tid >> 6);
  const int brow = blockIdx.x*128;
  const int wr = wid>>1, wc = wid&1;
  const ushort* A = Az + (size_t)t*Ats;

  f32x4 acc[4][4];
#pragma unroll
  for(int m=0;m<4;m++)
#pragma unroll
    for(int n=0;n<4;n++) acc[m][n] = (f32x4){0.f,0.f,0.f,0.f};

  for (int kt=0; kt<2; ++kt){
    stage_tile<128>(A + (size_t)brow*128 + kt*64, 128, Nrow-1-brow, As, lane, wid);
    stage_tile<128>(W + kt*64, 128, 1<<30, Bs, lane, wid);
    __syncthreads();
#pragma unroll
    for (int kk=0;kk<2;kk++){
      short8 a[4], b[4];
#pragma unroll
      for (int m=0;m<4;m++) a[m] = fragld(As, wr*64 + m*16 + (lane&15), kk, lane);
#pragma unroll
      for (int n=0;n<4;n++) b[n] = fragld(Bs, wc*64 + n*16 + (lane&15), kk, lane);
#pragma unroll
      for (int m=0;m<4;m++)
#pragma unroll
        for (int n=0;n<4;n++)
          acc[m][n] = __builtin_amdgcn_mfma_f32_16x16x32_bf16(a[m], b[n], acc[m][n], 0,0,0);
    }
    __syncthreads();
  }
  float sc[4], sb[4], w0_[4], w1_[4];
#pragma unroll
  for (int n=0;n<4;n++){
    int c = wc*64 + n*16 + (lane&15);
    bool ok = (c<100);
    sc[n] = ok? psc[c] : 0.f;
    sb[n] = ok? psb[c] : 0.f;
    w0_[n]= ok? W2[2*c] : 0.f;
    w1_[n]= ok? W2[2*c+1] : 0.f;
  }
#pragma unroll
  for (int m=0;m<4;m++){
#pragma unroll
    for (int q=0;q<4;q++){
      float a0=0.f, a1=0.f;
#pragma unroll
      for (int n=0;n<4;n++){
        float s = sigf(acc[m][n][q]*sc[n] + sb[n]);
        a0 += s*w0_[n]; a1 += s*w1_[n];
      }
#pragma unroll
      for (int o=1;o<16;o<<=1){ a0 += __shfl_xor(a0,o); a1 += __shfl_xor(a1,o); }
      if ((lane&15)==0){
        int rt = wr*64 + m*16 + (lane>>4)*4 + q;
        sh0[wc][rt] = a0; sh1[wc][rt] = a1;
      }
    }
  }
  __syncthreads();
  if (tid < 128){
    int r = brow + tid;
    if (r < Nrow){
      float l0 = sh0[0][tid]+sh0[1][tid]+b2[0];
      float l1 = sh1[0][tid]+sh1[1][tid]+b2[1];
      float mx = fmaxf(l0,l1);
      float e0 = expf(l0-mx), e1 = expf(l1-mx);
      float inv = 1.f/(e0+e1);
      psout[(size_t)t*psts + (size_t)r*2]   = e0*inv;
      psout[(size_t)t*psts + (size_t)r*2+1] = e1*inv;
    }
  }
}

// ================= CSR scan chain =================
__global__ void dinv_k(const uint* __restrict__ degcnt, int* __restrict__ cnt,
                       float* __restrict__ dnv, float* __restrict__ invd){
  int idx = blockIdx.x*256+threadIdx.x;
  if (idx>=TN) return;
  uint tot = degcnt[idx];
  int c = (int)(tot>>24);
  float S = (float)(tot & 0xFFFFFFu) * (1.f/262144.f);
  float dv = S + 1.f;
  cnt[idx] = c;
  dnv[idx]  = rsqrtf(dv);
  invd[idx] = 1.f/dv;
}

__global__ void scan1_k(const int* __restrict__ in, int* __restrict__ outv,
                        int* __restrict__ partials, int n)
{
  __shared__ int sh[256];
  int base = blockIdx.x*1024;
  int tid = threadIdx.x;
  int v[4]; int s=0;
#pragma unroll
  for (int i=0;i<4;i++){ int idx=base+tid*4+i; v[i] = (idx<n)? in[idx]:0; s+=v[i]; }
  sh[tid]=s; __syncthreads();
  for (int o=1;o<256;o<<=1){
    int t2 = (tid>=o)? sh[tid-o]:0;
    __syncthreads();
    sh[tid]+=t2;
    __syncthreads();
  }
  int excl = sh[tid]-s;
#pragma unroll
  for (int i=0;i<4;i++){ int idx=base+tid*4+i; if(idx<n) outv[idx]=excl; excl+=v[i]; }
  if (tid==255) partials[blockIdx.x]=sh[255];
}

__global__ void scan2_k(int* p, int np){
  __shared__ int sh[256];
  __shared__ int run;
  int tid=threadIdx.x;
  if(tid==0) run=0;
  __syncthreads();
  for(int base=0;base<np;base+=256){
    int v = (base+tid<np)? p[base+tid]:0;
    sh[tid]=v; __syncthreads();
    for(int o=1;o<256;o<<=1){
      int t2 = (tid>=o)? sh[tid-o]:0;
      __syncthreads();
      sh[tid]+=t2;
      __syncthreads();
    }
    int incl=sh[tid];
    int r0=run;
    __syncthreads();
    if(base+tid<np) p[base+tid]=r0+incl-v;
    __syncthreads();
    if(tid==0) run = r0 + sh[255];
    __syncthreads();
  }
}

__global__ void scan3_k(int* __restrict__ offs, const int* __restrict__ parts, int n){
  int idx = blockIdx.x*256+threadIdx.x;
  if (idx==0) offs[n] = TE;
  if (idx<n){ offs[idx] = offs[idx] + parts[idx>>10]; }
}

// ================= GCN gather (1D grid, t=bid&7 for XCD/t affinity) =============
__global__ __launch_bounds__(256) void gather_k(const int* __restrict__ offs,
    const uint* __restrict__ epack,
    const ushort* __restrict__ xwb, const float* __restrict__ invd,
    const float* __restrict__ gcb, ushort* __restrict__ rep)
{
  int bid  = blockIdx.x;
  int t    = bid & 7;
  int node = (bid>>3)*4 + (threadIdx.x>>6);
  int lane = threadIdx.x & 63;
  int half = lane>>5, ll = lane&31;
  if (node >= NN) return;
  const int* offs_t = offs + (size_t)t*NN;
  const ushort* xw_t = xwb + (size_t)t*NN*128;
  int o0 = offs_t[node], o1 = offs_t[node+1];
  float a0=0.f, a1=0.f, a2=0.f, a3=0.f;

  int j = o0 + half;
  for (; j+6 < o1; j += 8){
    uint e0 = epack[j],   e1 = epack[j+2];
    uint e2 = epack[j+4], e3 = epack[j+6];
    uint2 v0 = ((const uint2*)(xw_t + (size_t)(e0&0xffff)*128))[ll];
    uint2 v1 = ((const uint2*)(xw_t + (size_t)(e1&0xffff)*128))[ll];
    uint2 v2 = ((const uint2*)(xw_t + (size_t)(e2&0xffff)*128))[ll];
    uint2 v3 = ((const uint2*)(xw_t + (size_t)(e3&0xffff)*128))[ll];
    float n0 = (float)(e0>>16), n1 = (float)(e1>>16);
    float n2 = (float)(e2>>16), n3 = (float)(e3>>16);
    a0 = fmaf(n0, b2f((ushort)(v0.x&0xffff)), a0);
    a1 = fmaf(n0, b2f((ushort)(v0.x>>16)),   a1);
    a2 = fmaf(n0, b2f((ushort)(v0.y&0xffff)), a2);
    a3 = fmaf(n0, b2f((ushort)(v0.y>>16)),   a3);
    a0 = fmaf(n1, b2f((ushort)(v1.x&0xffff)), a0);
    a1 = fmaf(n1, b2f((ushort)(v1.x>>16)),   a1);
    a2 = fmaf(n1, b2f((ushort)(v1.y&0xffff)), a2);
    a3 = fmaf(n1, b2f((ushort)(v1.y>>16)),   a3);
    a0 = fmaf(n2, b2f((ushort)(v2.x&0xffff)), a0);
    a1 = fmaf(n2, b2f((ushort)(v2.x>>16)),   a1);
    a2 = fmaf(n2, b2f((ushort)(v2.y&0xffff)), a2);
    a3 = fmaf(n2, b2f((ushort)(v2.y>>16)),   a3);
    a0 = fmaf(n3, b2f((ushort)(v3.x&0xffff)), a0);
    a1 = fmaf(n3, b2f((ushort)(v3.x>>16)),   a1);
    a2 = fmaf(n3, b2f((ushort)(v3.y&0xffff)), a2);
    a3 = fmaf(n3, b2f((ushort)(v3.y>>16)),   a3);
  }
  for (; j < o1; j += 2){
    uint e0 = epack[j];
    uint2 v0 = ((const uint2*)(xw_t + (size_t)(e0&0xffff)*128))[ll];
    float n0 = (float)(e0>>16);
    a0 = fmaf(n0, b2f((ushort)(v0.x&0xffff)), a0);
    a1 = fmaf(n0, b2f((ushort)(v0.x>>16)),   a1);
    a2 = fmaf(n0, b2f((ushort)(v0.y&0xffff)), a2);
    a3 = fmaf(n0, b2f((ushort)(v0.y>>16)),   a3);
  }
  a0 += __shfl_xor(a0, 32);
  a1 += __shfl_xor(a1, 32);
  a2 += __shfl_xor(a2, 32);
  a3 += __shfl_xor(a3, 32);
  const float qs = 1.f/65535.f;
  a0 *= qs; a1 *= qs; a2 *= qs; a3 *= qs;
  float sl = invd[(size_t)t*NN + node];
  uint2 us = ((const uint2*)(xw_t + (size_t)node*128))[ll];
  float4 gb = ((const float4*)(gcb + (size_t)t*128))[ll];
  a0 = fmaf(sl, b2f((ushort)(us.x&0xffff)), a0) + gb.x;
  a1 = fmaf(sl, b2f((ushort)(us.x>>16)),   a1) + gb.y;
  a2 = fmaf(sl, b2f((ushort)(us.y&0xffff)), a2) + gb.z;
  a3 = fmaf(sl, b2f((ushort)(us.y>>16)),   a3) + gb.w;
  a0 = fmaxf(a0,0.f); a1 = fmaxf(a1,0.f);
  a2 = fmaxf(a2,0.f); a3 = fmaxf(a3,0.f);
  if (half==0){
    uint pk0 = (uint)f2b(a0) | ((uint)f2b(a1)<<16);
    uint pk1 = (uint)f2b(a2) | ((uint)f2b(a3)<<16);
    ((uint2*)(rep + ((size_t)t*NN + node)*128))[ll] = make_uint2(pk0, pk1);
  }
}

// ================= weight/activation prep =================
__global__ void convT_k(ushort* __restrict__ dst, const float* __restrict__ src,
                        int O, int Osrc, int K, int Kp)
{
  int idx = blockIdx.x*256 + threadIdx.x;
  if (idx >= O*Kp) return;
  dst += (size_t)blockIdx.y * O * Kp;
  src += (size_t)blockIdx.y * K * Osrc;
  int o = idx / Kp, k = idx - o*Kp;
  float v = (k<K && o<Osrc) ? src[(size_t)k*Osrc + o] : 0.f;
  dst[idx] = f2b(v);
}

__global__ void woc_k(ushort* __restrict__ dst, const float* __restrict__ o00W,
                      const float* __restrict__ o10W)
{
  int idx = blockIdx.x*256 + threadIdx.x;
  if (idx >= 256*128) return;
  int o = idx >> 7, k = idx & 127;
  float v = (o<128) ? o00W[(size_t)k*128 + o] : o10W[(size_t)k*128 + (o-128)];
  dst[idx] = f2b(v);
}

__global__ void wgru_k(const float* __restrict__ Wih, const float* __restrict__ Whh,
                       const float* __restrict__ bih, const float* __restrict__ bhh,
                       ushort* __restrict__ Wg, float* __restrict__ bg)
{
  int idx = blockIdx.x*256 + threadIdx.x;
  if (idx >= 1024*448) return;
  int c = idx/448, k = idx - c*448;
  int G = c>>6, g = (c>>4)&3, jj = c&15;
  int j = G*16 + jj;
  float v = 0.f;
  if (k < 152){
    if      (g==0) v = Wih[(size_t)j*152 + k];
    else if (g==1) v = Wih[(size_t)(256+j)*152 + k];
    else if (g==2) v = Wih[(size_t)(512+j)*152 + k];
  } else if (k >= 192){
    int kk = k-192;
    if      (g==0) v = Whh[(size_t)j*256 + kk];
    else if (g==1) v = Whh[(size_t)(256+j)*256 + kk];
    else if (g==3) v = Whh[(size_t)(512+j)*256 + kk];
  }
  Wg[idx] = f2b(v);
  if (k==0){
    float b;
    if      (g==0) b = bih[j]     + bhh[j];
    else if (g==1) b = bih[256+j] + bhh[256+j];
    else if (g==2) b = bih[512+j];
    else           b = bhh[512+j];
    bg[c] = b;
  }
}

__global__ void misc_k(const float* __restrict__ ps1b, const float* __restrict__ bng,
                       const float* __restrict__ bnb,
                       float* __restrict__ psc, float* __restrict__ psb)
{
  int i = threadIdx.x;
  if (i<100){ float sc = bng[i]*rsqrtf(1.f+1e-5f); psc[i]=sc; psb[i]=ps1b[i]*sc+bnb[i]; }
  else if (i<128){ psc[i]=0.f; psb[i]=0.f; }
}

// fill cyh_all[g][0:64] = [c(8) | yh(16) | zeros(40)] for all g = t*NN+n
__global__ void cyh_k(ushort* __restrict__ cyh, const float* __restrict__ Cc,
                      const float* __restrict__ Yh)
{
  long gid = (long)blockIdx.x*256 + threadIdx.x;   // TN*64
  if (gid >= (long)TN*64) return;
  long g = gid >> 6; int l = (int)(gid & 63);
  float v = 0.f;
  if (l < 8)       v = Cc[g*8 + l];
  else if (l < 24) v = Yh[g*16 + (l-8)];
  cyh[g*64 + l] = f2b(v);
}

extern "C" void kernel_launch(void* const* d_in, const int* in_sizes, int n_in,
                              void* d_out_v, int out_size, void* d_ws, size_t ws_size,
                              hipStream_t stream)
{
  const float* X    = (const float*)d_in[0];
  const float* Cc   = (const float*)d_in[1];
  const float* Yh   = (const float*)d_in[2];
  const int*   EI   = (const int*)  d_in[3];
  const float* phiW = (const float*)d_in[4];  const float* phib = (const float*)d_in[5];
  const float* gcW  = (const float*)d_in[6];  const float* gcb  = (const float*)d_in[7];
  const float* ewl  = (const float*)d_in[8];
  const float* fuseW= (const float*)d_in[9];  const float* fuseb= (const float*)d_in[10];
  const float* o00W = (const float*)d_in[11]; const float* o00b = (const float*)d_in[12];
  const float* o10W = (const float*)d_in[13]; const float* o10b = (const float*)d_in[14];
  const float* o01W = (const float*)d_in[15]; const float* o01b = (const float*)d_in[16];
  const float* o11W = (const float*)d_in[17]; const float* o11b = (const float*)d_in[18];
  const float* ps1W = (const float*)d_in[19]; const float* ps1b = (const float*)d_in[20];
  const float* bng  = (const float*)d_in[21]; const float* bnb  = (const float*)d_in[22];
  const float* ps2W = (const float*)d_in[23]; const float* ps2b = (const float*)d_in[24];
  const float* Wih  = (const float*)d_in[25]; const float* Whh  = (const float*)d_in[26];
  const float* bih  = (const float*)d_in[27]; const float* bhh  = (const float*)d_in[28];
  float* out = (float*)d_out_v;

  char* wsb = (char*)d_ws;
  size_t off=0;
  auto alloc=[&](size_t bytes)->void*{
    void* p = wsb + off;
    off = (off + bytes + 255) & ~(size_t)255;
    return p;
  };
  uint*  degcnt= (uint*) alloc((size_t)TN*4);
  int*   cnt   = (int*)  alloc((size_t)TN*4);
  int*   offs  = (int*)  alloc(((size_t)TN+1)*4);
  float* dnv   = (float*)alloc((size_t)TN*4);
  float* invd  = (float*)alloc((size_t)TN*4);
  uint*  epack = (uint*) alloc((size_t)TE*4);
  ushort* rankb= (ushort*)alloc((size_t)TE*2);
  int*   parts = (int*)  alloc(4096);
  ushort* rep_all = (ushort*)alloc((size_t)TN*128*2);
  ushort* phiA = (ushort*)alloc((size_t)TN*256*2);   // -> zbf_all + cyh_all after pz
  ushort* xwb  = (ushort*)alloc((size_t)TN*128*2);
  ushort* pz   = (ushort*)alloc((size_t)TN*128*2);
  ushort* hbf0 = (ushort*)alloc((size_t)NN*256*2);   // bf16 h ping-pong
  ushort* hbf1 = (ushort*)alloc((size_t)NN*256*2);
  float*  hb   = (float*)alloc((size_t)NN*256*4);    // fp32 h (in-place safe)
  ushort* phiWt= (ushort*)alloc(256*128*2);
  ushort* gcWt = (ushort*)alloc((size_t)T_STEPS*128*256*2);
  ushort* WhT  = (ushort*)alloc(128*256*2);
  ushort* WrpT = (ushort*)alloc(128*384*2);
  ushort* Wgru = (ushort*)alloc((size_t)1024*448*2);
  float* bgru  = (float*)alloc(1024*4);
  ushort* wocT = (ushort*)alloc(256*128*2);
  ushort* ps1T = (ushort*)alloc(128*128*2);
  float* psc   = (float*)alloc(128*4);
  float* psb   = (float*)alloc(128*4);

  ushort* zbf     = phiA;                            // TN x 128 (alias)
  ushort* cyh     = phiA + (size_t)TN*128;           // TN x 64  (alias)

  hipMemsetAsync(degcnt, 0, (size_t)TN*4, stream);
  hipMemsetAsync(hb,   0, (size_t)NN*256*4, stream);
  hipMemsetAsync(hbf0, 0, (size_t)NN*256*2, stream);

  // --- prep ---
  misc_k<<<1,256,0,stream>>>(ps1b,bng,bnb,psc,psb);
  convT_k<<<dim3((256*128+255)/256,1),256,0,stream>>>(phiWt, phiW, 256,256,128,128);
  convT_k<<<dim3((128*256+255)/256,T_STEPS),256,0,stream>>>(gcWt, gcW, 128,128,256,256);
  convT_k<<<dim3((128*256+255)/256,1),256,0,stream>>>(WhT, fuseW, 128,128,256,256);
  convT_k<<<dim3((128*384+255)/256,1),256,0,stream>>>(WrpT, fuseW+256*128, 128,128,384,384);
  convT_k<<<dim3((128*128+255)/256,1),256,0,stream>>>(ps1T, ps1W, 128,100,128,128);
  wgru_k<<<(1024*448+255)/256,256,0,stream>>>(Wih,Whh,bih,bhh,Wgru,bgru);
  woc_k<<<(256*128+255)/256,256,0,stream>>>(wocT, o00W, o10W);

  // --- [count ∥ phi] fused dispatch ---
  count_phi_k<<<CPB + GX*8, 512, 0, stream>>>(
    EI, ewl, degcnt, rankb, X, phiWt, phib, phiA, (long)NN*256, NN);
  // --- scan chain ---
  dinv_k<<<(TN+255)/256,256,0,stream>>>(degcnt,cnt,dnv,invd);
  scan1_k<<<(TN+1023)/1024,256,0,stream>>>(cnt,offs,parts,TN);
  scan2_k<<<1,256,0,stream>>>(parts,(TN+1023)/1024);
  scan3_k<<<(TN+255)/256,256,0,stream>>>(offs,parts,TN);
  // --- [fill ∥ xw] fused dispatch ---
  fill_xw_k<<<FPB + GX*8, 256, 0, stream>>>(
    EI, ewl, dnv, offs, rankb, epack, phiA, gcWt, xwb, NN);

  const size_t zoff  = (size_t)2*TN;
  const size_t psoff = zoff + (size_t)TN*128;
  const size_t hoff  = psoff + (size_t)TN*2;
  const Seg S0 = {nullptr,0,0,0};

  // rep_all (1D grid, t=bid&7)
  gather_k<<<(NN/4)*8,256,0,stream>>>(offs, epack, xwb, invd, gcb, rep_all);
  // pz_all = [rep_all | phi_all] @ [Wr;Wp]
  gemm_bf<<<dim3(GX,1,8),256,0,stream>>>(
    Seg{rep_all,128,(long)NN*128,128}, Seg{phiA,256,(long)NN*256,256}, S0,
    WrpT,384,0, nullptr,0,
    nullptr,0,0, nullptr,0,0, pz,128,(long)NN*128, NN,128);
  // cyh_all (overwrites upper phiA region; phi_all dead after pz)
  cyh_k<<<(int)(((long)TN*64+255)/256),256,0,stream>>>(cyh, Cc, Yh);

  // --- recurrent chain ---
  for (int t=0;t<T_STEPS;t++){
    const ushort* hbi = (t&1)? hbf1 : hbf0;
    ushort*       hbo = (t&1)? hbf0 : hbf1;
    float* hout = (t==T_STEPS-1)? (out+hoff) : hb;
    float* zt = out + zoff + (size_t)t*NN*128;
    ushort* zbt = zbf + (size_t)t*NN*128;
    // z = relu(h@Wh + pz_t + fuse_b) -> fp32 zt + bf16 zbf_t
    gemm_bf<<<dim3(GX,1,1),256,0,stream>>>(
      Seg{hbi,256,0,256}, S0, S0, WhT,256,0, fuseb,1,
      pz + (size_t)t*NN*128,128,0, zt,128,0, zbt,128,0, NN,128);
    // fused GRU -> h (fp32 in-place, bf16 ping-pong), 512 thr, 128x256 tiles
    gemm_gru512<<<dim3(GX,4),512,0,stream>>>(
      Seg{zbt,128,0,128}, Seg{cyh + (size_t)t*NN*64,64,0,64}, Seg{hbi,256,0,256},
      Wgru, bgru, hb, hout, hbo, NN);
  }

  // --- batched heads ---
  heads_k<<<dim3((NN+63)/64,1,8),256,0,stream>>>(
    zbf,(long)NN*128, wocT, o00b,o10b, o01W,o01b, o11W,o11b,
    out + TN, (long)NN,     // y0
    out, (long)NN, NN);     // y1
  ps_k<<<dim3(GX,1,8),256,0,stream>>>(
    zbf,(long)NN*128, ps1T, psc,psb, ps2W,ps2b,
    out+psoff, (long)NN*2, NN);

  (void)in_sizes; (void)n_in; (void)out_size; (void)ws_size;
}

// Round 13
// 2279.490 us; speedup vs baseline: 1.0177x; 1.0177x over previous
//
#include <hip/hip_runtime.h>
#include <math.h>

#define T_STEPS 8
#define NN 50000
#define EE 800000
#define TN (T_STEPS*NN)   // 400000
#define TE (T_STEPS*EE)   // 6400000
#define GX 391            // (NN+127)/128

typedef unsigned int uint;
typedef unsigned short ushort;
typedef unsigned long long u64;
typedef __attribute__((ext_vector_type(8))) short short8;
typedef __attribute__((ext_vector_type(4))) float f32x4;

__device__ __forceinline__ float sigf(float x){ return 1.0f/(1.0f+expf(-x)); }
__device__ __forceinline__ ushort f2b(float f){
  uint x = __float_as_uint(f);
  uint r = (x + 0x7fffu + ((x>>16)&1u)) >> 16;
  return (ushort)r;
}
__device__ __forceinline__ float b2f(ushort u){ return __uint_as_float(((uint)u)<<16); }

__device__ __forceinline__ void gload16(const ushort* g, ushort* l){
  __builtin_amdgcn_global_load_lds(
      (const __attribute__((address_space(1))) void*)g,
      (__attribute__((address_space(3))) void*)l, 16, 0, 0);
}

// stage ROWS x 64 bf16 tile into LDS (pre-swizzled source, linear dest), 256 thr
template<int ROWS>
__device__ __forceinline__ void stage_tile(const ushort* base, int ld, int rowclamp,
                                           ushort* lds, int lane, int wid){
  constexpr int ITERS = ROWS/32;
#pragma unroll
  for (int i=0;i<ITERS;i++){
    int lin = i*256 + wid*64 + lane;
    int row = lin>>3, s = lin&7;
    int gr = row; if (gr > rowclamp) gr = rowclamp;
    const ushort* gp = base + (size_t)gr*ld + ((s ^ (row&7))<<3);
    gload16(gp, lds + (size_t)(i*256 + wid*64)*8);
  }
}

// same, for 512-thread blocks
template<int ROWS>
__device__ __forceinline__ void stage512(const ushort* base, int ld, int rowclamp,
                                         ushort* lds, int tid){
  constexpr int ITERS = ROWS/64;
#pragma unroll
  for (int i=0;i<ITERS;i++){
    int lin = i*512 + tid;
    int row = lin>>3, s = lin&7;
    int gr = row; if (gr > rowclamp) gr = rowclamp;
    const ushort* gp = base + (size_t)gr*ld + ((s ^ (row&7))<<3);
    gload16(gp, lds + (size_t)lin*8);
  }
}

__device__ __forceinline__ short8 fragld(const ushort* lds, int R, int kk, int lane){
  int slot = (kk*4 + (lane>>4)) ^ (R&7);
  return *(const short8*)&lds[R*64 + slot*8];
}

struct Seg { const ushort* p; int ld; long ts; int w; };

// ================= generic bf16 MFMA GEMM (128x128 tile, 3-seg A, batched t) ======
__global__ __launch_bounds__(256,2) void gemm_bf(
    Seg s0, Seg s1, Seg s2,
    const ushort* __restrict__ W, int K2, long Wts,
    const float* __restrict__ bias, int act,
    const ushort* __restrict__ addp, int ldad, long adts,
    float* __restrict__ C32, int ldc, long c32ts,
    ushort* __restrict__ C16, int ldb, long c16ts,
    int Nrow, int NOvalid)
{
  __shared__ __align__(16) ushort As[8192];
  __shared__ __align__(16) ushort Bs[8192];
  const int t    = blockIdx.z;
  const int tid  = threadIdx.x;
  const int lane = tid & 63;
  const int wid  = __builtin_amdgcn_readfirstlane(tid >> 6);
  const int brow = blockIdx.x*128;
  const int bcol = blockIdx.y*128;
  const int wr = wid>>1, wc = wid&1;

  f32x4 acc[4][4];
#pragma unroll
  for(int m=0;m<4;m++)
#pragma unroll
    for(int n=0;n<4;n++) acc[m][n] = (f32x4){0.f,0.f,0.f,0.f};

  const int nk = K2 >> 6;
  for (int kt=0; kt<nk; ++kt){
    int col0 = kt*64;
    const ushort* ab; int ald;
    if (col0 < s0.w){ ab = s0.p + (size_t)t*s0.ts + col0; ald = s0.ld; }
    else if (col0 < s0.w + s1.w){ ab = s1.p + (size_t)t*s1.ts + (col0 - s0.w); ald = s1.ld; }
    else { ab = s2.p + (size_t)t*s2.ts + (col0 - s0.w - s1.w); ald = s2.ld; }
    stage_tile<128>(ab + (size_t)brow*ald, ald, Nrow-1-brow, As, lane, wid);
    stage_tile<128>(W + (size_t)t*Wts + (size_t)bcol*K2 + col0, K2, 1<<30, Bs, lane, wid);
    __syncthreads();
#pragma unroll
    for (int kk=0;kk<2;kk++){
      short8 a[4], b[4];
#pragma unroll
      for (int m=0;m<4;m++) a[m] = fragld(As, wr*64 + m*16 + (lane&15), kk, lane);
#pragma unroll
      for (int n=0;n<4;n++) b[n] = fragld(Bs, wc*64 + n*16 + (lane&15), kk, lane);
#pragma unroll
      for (int m=0;m<4;m++)
#pragma unroll
        for (int n=0;n<4;n++)
          acc[m][n] = __builtin_amdgcn_mfma_f32_16x16x32_bf16(a[m], b[n], acc[m][n], 0,0,0);
    }
    __syncthreads();
  }
  const int rbase = brow + wr*64 + (lane>>4)*4;
  const int cbase = bcol + wc*64 + (lane&15);
#pragma unroll
  for (int m=0;m<4;m++){
#pragma unroll
    for (int q=0;q<4;q++){
      int r = rbase + m*16 + q;
      if (r >= Nrow) continue;
#pragma unroll
      for (int n=0;n<4;n++){
        int c = cbase + n*16;
        if (c >= NOvalid) continue;
        float v = acc[m][n][q];
        if (addp) v += b2f(addp[(size_t)t*adts + (size_t)r*ldad + c]);
        if (bias) v += bias[c];
        if (act==1) v = fmaxf(v, 0.f);
        if (C32) C32[(size_t)t*c32ts + (size_t)r*ldc + c] = v;
        if (C16) C16[(size_t)t*c16ts + (size_t)r*ldb + c] = f2b(v);
      }
    }
  }
}

// ====== phi GEMM: 512 thr, 128 rows x 256 cols, reads fp32 X directly ============
__global__ __launch_bounds__(512,2) void gemm_phi512(
    const float* __restrict__ A32,          // X [t][NN][128] fp32
    const ushort* __restrict__ W,           // phiWt [256][128]
    const float* __restrict__ bias,
    ushort* __restrict__ C16, long c16ts,   // phiA ld 256
    int Nrow)
{
  __shared__ __align__(16) ushort As[8192];    // 128 x 64
  __shared__ __align__(16) ushort Bs[16384];   // 256 x 64
  const int t    = blockIdx.z;
  const int tid  = threadIdx.x;
  const int lane = tid & 63;
  const int wid  = __builtin_amdgcn_readfirstlane(tid >> 6);
  const int brow = blockIdx.x*128;
  const int wr = wid>>2, wc = wid&3;           // 2 x 4 wave grid
  const float* At = A32 + (size_t)t*NN*128;

  f32x4 acc[4][4];
#pragma unroll
  for(int m=0;m<4;m++)
#pragma unroll
    for(int n=0;n<4;n++) acc[m][n] = (f32x4){0.f,0.f,0.f,0.f};

  for (int kt=0; kt<2; ++kt){
    int col0 = kt*64;
#pragma unroll
    for (int it=0; it<4; ++it){
      int lin = it*512 + tid;          // float4 unit, 0..2047
      int row = lin>>4, q4 = lin&15;
      int grow = brow + row; if (grow >= Nrow) grow = Nrow-1;
      float4 v = *(const float4*)&At[(size_t)grow*128 + col0 + q4*4];
      int s = q4>>1, half = q4&1;
      uint lo = (uint)f2b(v.x) | ((uint)f2b(v.y)<<16);
      uint hi = (uint)f2b(v.z) | ((uint)f2b(v.w)<<16);
      *(uint2*)&As[row*64 + ((s ^ (row&7))<<3) + half*4] = make_uint2(lo,hi);
    }
    stage512<256>(W + col0, 128, 1<<30, Bs, tid);
    __syncthreads();
#pragma unroll
    for (int kk=0;kk<2;kk++){
      short8 a[4], b[4];
#pragma unroll
      for (int m=0;m<4;m++) a[m] = fragld(As, wr*64 + m*16 + (lane&15), kk, lane);
#pragma unroll
      for (int n=0;n<4;n++) b[n] = fragld(Bs, wc*64 + n*16 + (lane&15), kk, lane);
#pragma unroll
      for (int m=0;m<4;m++)
#pragma unroll
        for (int n=0;n<4;n++)
          acc[m][n] = __builtin_amdgcn_mfma_f32_16x16x32_bf16(a[m], b[n], acc[m][n], 0,0,0);
    }
    __syncthreads();
  }
  const int rbase = brow + wr*64 + (lane>>4)*4;
  const int cbase = wc*64 + (lane&15);
#pragma unroll
  for (int m=0;m<4;m++){
#pragma unroll
    for (int q=0;q<4;q++){
      int r = rbase + m*16 + q;
      if (r >= Nrow) continue;
#pragma unroll
      for (int n=0;n<4;n++){
        int c = cbase + n*16;
        float v = acc[m][n][q] + bias[c];
        v = fmaxf(v, 0.f);
        C16[(size_t)t*c16ts + (size_t)r*256 + c] = f2b(v);
      }
    }
  }
}

// ====== fused GRU GEMM, 512 threads, 128 rows x 256 gate-cols, 2x4 wave grid =====
__global__ __launch_bounds__(512,2) void gemm_gru512(
    Seg s0, Seg s1, Seg s2,
    const ushort* __restrict__ W,                        // Wgru [1024][448]
    const float* __restrict__ bg,                        // [1024]
    const float* __restrict__ hin,                       // fp32 h_t
    float* __restrict__ hout, ushort* __restrict__ hbfo, // hbfo != s2.p (ping-pong!)
    int Nrow)
{
  __shared__ __align__(16) ushort As[8192];    // 128 x 64
  __shared__ __align__(16) ushort Bs[16384];   // 256 x 64
  const int tid  = threadIdx.x;
  const int lane = tid & 63;
  const int wid  = __builtin_amdgcn_readfirstlane(tid >> 6);   // 0..7
  const int brow = blockIdx.x*128;
  const int bcol = blockIdx.y*256;
  const int wr = wid>>2, wc = wid&3;           // 2 x 4 wave grid
  const int K2 = 448;

  f32x4 acc[4][4];
#pragma unroll
  for(int m=0;m<4;m++)
#pragma unroll
    for(int n=0;n<4;n++) acc[m][n] = (f32x4){0.f,0.f,0.f,0.f};

  for (int kt=0; kt<7; ++kt){
    int col0 = kt*64;
    const ushort* ab; int ald;
    if (col0 < s0.w){ ab = s0.p + col0; ald = s0.ld; }
    else if (col0 < s0.w + s1.w){ ab = s1.p + (col0 - s0.w); ald = s1.ld; }
    else { ab = s2.p + (col0 - s0.w - s1.w); ald = s2.ld; }
    stage512<128>(ab + (size_t)brow*ald, ald, Nrow-1-brow, As, tid);
    stage512<256>(W + (size_t)bcol*K2 + col0, K2, 1<<30, Bs, tid);
    __syncthreads();
#pragma unroll
    for (int kk=0;kk<2;kk++){
      short8 a[4], b[4];
#pragma unroll
      for (int m=0;m<4;m++) a[m] = fragld(As, wr*64 + m*16 + (lane&15), kk, lane);
#pragma unroll
      for (int n=0;n<4;n++) b[n] = fragld(Bs, wc*64 + n*16 + (lane&15), kk, lane);
#pragma unroll
      for (int m=0;m<4;m++)
#pragma unroll
        for (int n=0;n<4;n++)
          acc[m][n] = __builtin_amdgcn_mfma_f32_16x16x32_bf16(a[m], b[n], acc[m][n], 0,0,0);
    }
    __syncthreads();
  }
  // c = bcol + wc*64 + n*16 + jj ; G = c>>6 = y*4+wc ; j = G*16+jj ; gate = n
  const int jj = lane&15;
  const int G  = blockIdx.y*4 + wc;
  const int j  = G*16 + jj;
  const int rbase = brow + wr*64 + (lane>>4)*4;
  float bb[4];
#pragma unroll
  for (int n=0;n<4;n++) bb[n] = bg[G*64 + n*16 + jj];
#pragma unroll
  for (int m=0;m<4;m++){
#pragma unroll
    for (int q=0;q<4;q++){
      int r = rbase + m*16 + q;
      if (r >= Nrow) continue;
      float v0 = acc[m][0][q] + bb[0];
      float v1 = acc[m][1][q] + bb[1];
      float v2 = acc[m][2][q] + bb[2];
      float v3 = acc[m][3][q] + bb[3];
      float rg = sigf(v0), ug = sigf(v1);
      float ng = tanhf(v2 + rg*v3);
      float ho = hin[(size_t)r*256 + j];
      float hn = (1.f-ug)*ng + ug*ho;
      hout[(size_t)r*256 + j] = hn;
      hbfo[(size_t)r*256 + j] = f2b(hn);
    }
  }
}

// ================= fused outcome heads (batched over t) ==============
__global__ __launch_bounds__(256,2) void heads_k(
    const ushort* __restrict__ Az, long Ats,             // zbf_all, ld 128
    const ushort* __restrict__ W,                        // wocT [256][128]
    const float* __restrict__ o00b, const float* __restrict__ o10b,
    const float* __restrict__ w01, const float* __restrict__ b01,
    const float* __restrict__ w11, const float* __restrict__ b11,
    float* __restrict__ y0out, long y0ts,
    float* __restrict__ y1out, long y1ts, int Nrow)
{
  __shared__ __align__(16) ushort As[4096];
  __shared__ __align__(16) ushort Bs[16384];
  __shared__ float shy[4][64];
  const int t    = blockIdx.z;
  const int tid  = threadIdx.x;
  const int lane = tid & 63;
  const int wid  = __builtin_amdgcn_readfirstlane(tid >> 6);
  const int brow = blockIdx.x*64;
  const ushort* A = Az + (size_t)t*Ats;

  f32x4 acc[4][4];
#pragma unroll
  for(int m=0;m<4;m++)
#pragma unroll
    for(int n=0;n<4;n++) acc[m][n] = (f32x4){0.f,0.f,0.f,0.f};

  for (int kt=0; kt<2; ++kt){
    stage_tile<64>(A + (size_t)brow*128 + kt*64, 128, Nrow-1-brow, As, lane, wid);
    stage_tile<256>(W + kt*64, 128, 1<<30, Bs, lane, wid);
    __syncthreads();
#pragma unroll
    for (int kk=0;kk<2;kk++){
      short8 a[4], b[4];
#pragma unroll
      for (int m=0;m<4;m++) a[m] = fragld(As, m*16 + (lane&15), kk, lane);
#pragma unroll
      for (int n=0;n<4;n++) b[n] = fragld(Bs, wid*64 + n*16 + (lane&15), kk, lane);
#pragma unroll
      for (int m=0;m<4;m++)
#pragma unroll
        for (int n=0;n<4;n++)
          acc[m][n] = __builtin_amdgcn_mfma_f32_16x16x32_bf16(a[m], b[n], acc[m][n], 0,0,0);
    }
    __syncthreads();
  }
  float bb[4], ww[4];
#pragma unroll
  for (int n=0;n<4;n++){
    int c = wid*64 + n*16 + (lane&15);
    bb[n] = (c<128)? o00b[c] : o10b[c-128];
    ww[n] = (c<128)? w01[c]  : w11[c-128];
  }
#pragma unroll
  for (int m=0;m<4;m++){
#pragma unroll
    for (int q=0;q<4;q++){
      float p = 0.f;
#pragma unroll
      for (int n=0;n<4;n++) p += fmaxf(acc[m][n][q] + bb[n], 0.f) * ww[n];
#pragma unroll
      for (int o=1;o<16;o<<=1) p += __shfl_xor(p, o);
      if ((lane&15)==0) shy[wid][m*16 + (lane>>4)*4 + q] = p;
    }
  }
  __syncthreads();
  if (tid < 64){
    int r = brow + tid;
    if (r < Nrow){
      y0out[(size_t)t*y0ts + r] = shy[0][tid] + shy[1][tid] + b01[0];
      y1out[(size_t)t*y1ts + r] = shy[2][tid] + shy[3][tid] + b11[0];
    }
  }
}

// ================= fused propensity head (batched over t) ==============
__global__ __launch_bounds__(256,2) void ps_k(
    const ushort* __restrict__ Az, long Ats,             // zbf_all, ld 128
    const ushort* __restrict__ W,                        // ps1T [128][128]
    const float* __restrict__ psc, const float* __restrict__ psb,
    const float* __restrict__ W2, const float* __restrict__ b2,
    float* __restrict__ psout, long psts, int Nrow)
{
  __shared__ __align__(16) ushort As[8192];
  __shared__ __align__(16) ushort Bs[8192];
  __shared__ float sh0[2][128];
  __shared__ float sh1[2][128];
  const int t    = blockIdx.z;
  const int tid  = threadIdx.x;
  const int lane = tid & 63;
  const int wid  = __builtin_amdgcn_readfirstlane(tid >> 6);
  const int brow = blockIdx.x*128;
  const int wr = wid>>1, wc = wid&1;
  const ushort* A = Az + (size_t)t*Ats;

  f32x4 acc[4][4];
#pragma unroll
  for(int m=0;m<4;m++)
#pragma unroll
    for(int n=0;n<4;n++) acc[m][n] = (f32x4){0.f,0.f,0.f,0.f};

  for (int kt=0; kt<2; ++kt){
    stage_tile<128>(A + (size_t)brow*128 + kt*64, 128, Nrow-1-brow, As, lane, wid);
    stage_tile<128>(W + kt*64, 128, 1<<30, Bs, lane, wid);
    __syncthreads();
#pragma unroll
    for (int kk=0;kk<2;kk++){
      short8 a[4], b[4];
#pragma unroll
      for (int m=0;m<4;m++) a[m] = fragld(As, wr*64 + m*16 + (lane&15), kk, lane);
#pragma unroll
      for (int n=0;n<4;n++) b[n] = fragld(Bs, wc*64 + n*16 + (lane&15), kk, lane);
#pragma unroll
      for (int m=0;m<4;m++)
#pragma unroll
        for (int n=0;n<4;n++)
          acc[m][n] = __builtin_amdgcn_mfma_f32_16x16x32_bf16(a[m], b[n], acc[m][n], 0,0,0);
    }
    __syncthreads();
  }
  float sc[4], sb[4], w0_[4], w1_[4];
#pragma unroll
  for (int n=0;n<4;n++){
    int c = wc*64 + n*16 + (lane&15);
    bool ok = (c<100);
    sc[n] = ok? psc[c] : 0.f;
    sb[n] = ok? psb[c] : 0.f;
    w0_[n]= ok? W2[2*c] : 0.f;
    w1_[n]= ok? W2[2*c+1] : 0.f;
  }
#pragma unroll
  for (int m=0;m<4;m++){
#pragma unroll
    for (int q=0;q<4;q++){
      float a0=0.f, a1=0.f;
#pragma unroll
      for (int n=0;n<4;n++){
        float s = sigf(acc[m][n][q]*sc[n] + sb[n]);
        a0 += s*w0_[n]; a1 += s*w1_[n];
      }
#pragma unroll
      for (int o=1;o<16;o<<=1){ a0 += __shfl_xor(a0,o); a1 += __shfl_xor(a1,o); }
      if ((lane&15)==0){
        int rt = wr*64 + m*16 + (lane>>4)*4 + q;
        sh0[wc][rt] = a0; sh1[wc][rt] = a1;
      }
    }
  }
  __syncthreads();
  if (tid < 128){
    int r = brow + tid;
    if (r < Nrow){
      float l0 = sh0[0][tid]+sh0[1][tid]+b2[0];
      float l1 = sh1[0][tid]+sh1[1][tid]+b2[1];
      float mx = fmaxf(l0,l1);
      float e0 = expf(l0-mx), e1 = expf(l1-mx);
      float inv = 1.f/(e0+e1);
      psout[(size_t)t*psts + (size_t)r*2]   = e0*inv;
      psout[(size_t)t*psts + (size_t)r*2+1] = e1*inv;
    }
  }
}

// ================= CSR build =================
// u32 atomic: count in bits[31:24] (max deg ~40 << 255), sum q18 in [23:0].
__global__ void count_k(const int* __restrict__ ei, const float* __restrict__ ewl,
                        uint* __restrict__ degcnt, ushort* __restrict__ rank)
{
  int idx = blockIdx.x*256 + threadIdx.x;
  if (idx >= TE) return;
  int t = idx / EE;
  int e = idx - t*EE;
  const int* dst = ei + (size_t)t*2*EE + EE;
  int d = dst[e];
  uint v = (1u<<24) | (uint)(sigf(ewl[idx]) * 262144.0f);
  uint old = atomicAdd(&degcnt[t*NN + d], v);
  rank[idx] = (ushort)(old>>24);
}

__global__ void dinv_k(const uint* __restrict__ degcnt, int* __restrict__ cnt,
                       float* __restrict__ dnv, float* __restrict__ invd){
  int idx = blockIdx.x*256+threadIdx.x;
  if (idx>=TN) return;
  uint tot = degcnt[idx];
  int c = (int)(tot>>24);
  float S = (float)(tot & 0xFFFFFFu) * (1.f/262144.f);
  float dv = S + 1.f;
  cnt[idx] = c;
  dnv[idx]  = rsqrtf(dv);
  invd[idx] = 1.f/dv;
}

__global__ void scan1_k(const int* __restrict__ in, int* __restrict__ outv,
                        int* __restrict__ partials, int n)
{
  __shared__ int sh[256];
  int base = blockIdx.x*1024;
  int tid = threadIdx.x;
  int v[4]; int s=0;
#pragma unroll
  for (int i=0;i<4;i++){ int idx=base+tid*4+i; v[i] = (idx<n)? in[idx]:0; s+=v[i]; }
  sh[tid]=s; __syncthreads();
  for (int o=1;o<256;o<<=1){
    int t2 = (tid>=o)? sh[tid-o]:0;
    __syncthreads();
    sh[tid]+=t2;
    __syncthreads();
  }
  int excl = sh[tid]-s;
#pragma unroll
  for (int i=0;i<4;i++){ int idx=base+tid*4+i; if(idx<n) outv[idx]=excl; excl+=v[i]; }
  if (tid==255) partials[blockIdx.x]=sh[255];
}

__global__ void scan2_k(int* p, int np){
  __shared__ int sh[256];
  __shared__ int run;
  int tid=threadIdx.x;
  if(tid==0) run=0;
  __syncthreads();
  for(int base=0;base<np;base+=256){
    int v = (base+tid<np)? p[base+tid]:0;
    sh[tid]=v; __syncthreads();
    for(int o=1;o<256;o<<=1){
      int t2 = (tid>=o)? sh[tid-o]:0;
      __syncthreads();
      sh[tid]+=t2;
      __syncthreads();
    }
    int incl=sh[tid];
    int r0=run;
    __syncthreads();
    if(base+tid<np) p[base+tid]=r0+incl-v;
    __syncthreads();
    if(tid==0) run = r0 + sh[255];
    __syncthreads();
  }
}

__global__ void scan3_k(int* __restrict__ offs, const int* __restrict__ parts, int n){
  int idx = blockIdx.x*256+threadIdx.x;
  if (idx==0) offs[n] = TE;
  if (idx<n){ offs[idx] = offs[idx] + parts[idx>>10]; }
}

// atomic-free fill: pos = offs[dst] + rank
__global__ void fill_k(const int* __restrict__ ei, const float* __restrict__ ewl,
                       const float* __restrict__ dnv, const int* __restrict__ offs,
                       const ushort* __restrict__ rank, uint* __restrict__ epack)
{
  int idx = blockIdx.x*256 + threadIdx.x;
  if (idx >= TE) return;
  int t = idx / EE;
  int e = idx - t*EE;
  const int* srcp = ei + (size_t)t*2*EE;
  const int* dstp = srcp + EE;
  int s=srcp[e], d=dstp[e];
  float nr = dnv[t*NN+s] * sigf(ewl[idx]) * dnv[t*NN+d];
  uint nq = (uint)(nr*65535.f + 0.5f);
  int pos = offs[t*NN+d] + rank[idx];
  epack[pos] = (uint)s | (nq<<16);
}

// ================= GCN gather (1D grid, t=bid&7 for XCD/t affinity) =============
// unpack opt: lo = bits<<16, hi = bits&0xffff0000 (bit-exact vs b2f, 1 op each)
__global__ __launch_bounds__(256) void gather_k(const int* __restrict__ offs,
    const uint* __restrict__ epack,
    const ushort* __restrict__ xwb, const float* __restrict__ invd,
    const float* __restrict__ gcb, ushort* __restrict__ rep)
{
  int bid  = blockIdx.x;
  int t    = bid & 7;
  int node = (bid>>3)*4 + (threadIdx.x>>6);
  int lane = threadIdx.x & 63;
  int half = lane>>5, ll = lane&31;
  if (node >= NN) return;
  const int* offs_t = offs + (size_t)t*NN;
  const ushort* xw_t = xwb + (size_t)t*NN*128;
  int o0 = offs_t[node], o1 = offs_t[node+1];
  float a0=0.f, a1=0.f, a2=0.f, a3=0.f;

#define ACC4(nv, uv) \
    a0 = fmaf(nv, __uint_as_float((uv).x<<16),          a0); \
    a1 = fmaf(nv, __uint_as_float((uv).x & 0xffff0000u), a1); \
    a2 = fmaf(nv, __uint_as_float((uv).y<<16),          a2); \
    a3 = fmaf(nv, __uint_as_float((uv).y & 0xffff0000u), a3);

  int j = o0 + half;
  for (; j+6 < o1; j += 8){
    uint e0 = epack[j],   e1 = epack[j+2];
    uint e2 = epack[j+4], e3 = epack[j+6];
    uint2 v0 = ((const uint2*)(xw_t + (size_t)(e0&0xffff)*128))[ll];
    uint2 v1 = ((const uint2*)(xw_t + (size_t)(e1&0xffff)*128))[ll];
    uint2 v2 = ((const uint2*)(xw_t + (size_t)(e2&0xffff)*128))[ll];
    uint2 v3 = ((const uint2*)(xw_t + (size_t)(e3&0xffff)*128))[ll];
    float n0 = (float)(e0>>16), n1 = (float)(e1>>16);
    float n2 = (float)(e2>>16), n3 = (float)(e3>>16);
    ACC4(n0, v0)
    ACC4(n1, v1)
    ACC4(n2, v2)
    ACC4(n3, v3)
  }
  for (; j < o1; j += 2){
    uint e0 = epack[j];
    uint2 v0 = ((const uint2*)(xw_t + (size_t)(e0&0xffff)*128))[ll];
    float n0 = (float)(e0>>16);
    ACC4(n0, v0)
  }
#undef ACC4
  a0 += __shfl_xor(a0, 32);
  a1 += __shfl_xor(a1, 32);
  a2 += __shfl_xor(a2, 32);
  a3 += __shfl_xor(a3, 32);
  const float qs = 1.f/65535.f;
  a0 *= qs; a1 *= qs; a2 *= qs; a3 *= qs;
  float sl = invd[(size_t)t*NN + node];
  uint2 us = ((const uint2*)(xw_t + (size_t)node*128))[ll];
  float4 gb = ((const float4*)(gcb + (size_t)t*128))[ll];
  a0 = fmaf(sl, __uint_as_float(us.x<<16),           a0) + gb.x;
  a1 = fmaf(sl, __uint_as_float(us.x & 0xffff0000u), a1) + gb.y;
  a2 = fmaf(sl, __uint_as_float(us.y<<16),           a2) + gb.z;
  a3 = fmaf(sl, __uint_as_float(us.y & 0xffff0000u), a3) + gb.w;
  a0 = fmaxf(a0,0.f); a1 = fmaxf(a1,0.f);
  a2 = fmaxf(a2,0.f); a3 = fmaxf(a3,0.f);
  if (half==0){
    uint pk0 = (uint)f2b(a0) | ((uint)f2b(a1)<<16);
    uint pk1 = (uint)f2b(a2) | ((uint)f2b(a3)<<16);
    ((uint2*)(rep + ((size_t)t*NN + node)*128))[ll] = make_uint2(pk0, pk1);
  }
}

// ================= single fused weight-prep kernel =================
// block ranges: [0,128) phiWt | [128,1152) gcWt | [1152,1280) WhT |
// [1280,1472) WrpT | [1472,1536) ps1T | [1536,3328) Wgru | [3328,3456) wocT |
// [3456] misc
__global__ __launch_bounds__(256) void prep_k(
    const float* __restrict__ phiW, const float* __restrict__ gcW,
    const float* __restrict__ fuseW, const float* __restrict__ ps1W,
    const float* __restrict__ Wih, const float* __restrict__ Whh,
    const float* __restrict__ bih, const float* __restrict__ bhh,
    const float* __restrict__ o00W, const float* __restrict__ o10W,
    const float* __restrict__ ps1b, const float* __restrict__ bng,
    const float* __restrict__ bnb,
    ushort* __restrict__ phiWt, ushort* __restrict__ gcWt,
    ushort* __restrict__ WhT, ushort* __restrict__ WrpT,
    ushort* __restrict__ ps1T, ushort* __restrict__ Wg,
    float* __restrict__ bg, ushort* __restrict__ wocT,
    float* __restrict__ psc, float* __restrict__ psb)
{
  const int bid = blockIdx.x;
  const int tid = threadIdx.x;
  if (bid < 128){                         // phiWt[o][k] = phiW[k][o], 256x128
    int idx = bid*256 + tid;
    int o = idx>>7, k = idx&127;
    phiWt[idx] = f2b(phiW[(size_t)k*256 + o]);
  } else if (bid < 1152){                 // gcWt[t][o][k] = gcW[t][k][o], 8x128x256
    int idx = (bid-128)*256 + tid;
    int t = idx>>15, rem = idx&32767, o = rem>>8, k = rem&255;
    gcWt[idx] = f2b(gcW[(size_t)t*32768 + (size_t)k*128 + o]);
  } else if (bid < 1280){                 // WhT[o][k] = fuseW[k][o], 128x256
    int idx = (bid-1152)*256 + tid;
    int o = idx>>8, k = idx&255;
    WhT[idx] = f2b(fuseW[(size_t)k*128 + o]);
  } else if (bid < 1472){                 // WrpT[o][k] = fuseW[256+k][o], 128x384
    int idx = (bid-1280)*256 + tid;
    int o = idx/384, k = idx - o*384;
    WrpT[idx] = f2b(fuseW[32768 + (size_t)k*128 + o]);
  } else if (bid < 1536){                 // ps1T[o][k] = ps1W[k][o] (o<100), 128x128
    int idx = (bid-1472)*256 + tid;
    int o = idx>>7, k = idx&127;
    ps1T[idx] = f2b((o<100)? ps1W[(size_t)k*100 + o] : 0.f);
  } else if (bid < 3328){                 // Wgru 1024x448
    int idx = (bid-1536)*256 + tid;
    int c = idx/448, k = idx - c*448;
    int G = c>>6, g = (c>>4)&3, jj = c&15;
    int j = G*16 + jj;
    float v = 0.f;
    if (k < 152){
      if      (g==0) v = Wih[(size_t)j*152 + k];
      else if (g==1) v = Wih[(size_t)(256+j)*152 + k];
      else if (g==2) v = Wih[(size_t)(512+j)*152 + k];
    } else if (k >= 192){
      int kk = k-192;
      if      (g==0) v = Whh[(size_t)j*256 + kk];
      else if (g==1) v = Whh[(size_t)(256+j)*256 + kk];
      else if (g==3) v = Whh[(size_t)(512+j)*256 + kk];
    }
    Wg[idx] = f2b(v);
    if (k==0){
      float b;
      if      (g==0) b = bih[j]     + bhh[j];
      else if (g==1) b = bih[256+j] + bhh[256+j];
      else if (g==2) b = bih[512+j];
      else           b = bhh[512+j];
      bg[c] = b;
    }
  } else if (bid < 3456){                 // wocT 256x128
    int idx = (bid-3328)*256 + tid;
    int o = idx>>7, k = idx&127;
    float v = (o<128) ? o00W[(size_t)k*128 + o] : o10W[(size_t)k*128 + (o-128)];
    wocT[idx] = f2b(v);
  } else {                                // misc
    int i = tid;
    if (i<100){ float sc = bng[i]*rsqrtf(1.f+1e-5f); psc[i]=sc; psb[i]=ps1b[i]*sc+bnb[i]; }
    else if (i<128){ psc[i]=0.f; psb[i]=0.f; }
  }
}

// fill cyh_all[g][0:64] = [c(8) | yh(16) | zeros(40)] for all g = t*NN+n
__global__ void cyh_k(ushort* __restrict__ cyh, const float* __restrict__ Cc,
                      const float* __restrict__ Yh)
{
  long gid = (long)blockIdx.x*256 + threadIdx.x;   // TN*64
  if (gid >= (long)TN*64) return;
  long g = gid >> 6; int l = (int)(gid & 63);
  float v = 0.f;
  if (l < 8)       v = Cc[g*8 + l];
  else if (l < 24) v = Yh[g*16 + (l-8)];
  cyh[g*64 + l] = f2b(v);
}

extern "C" void kernel_launch(void* const* d_in, const int* in_sizes, int n_in,
                              void* d_out_v, int out_size, void* d_ws, size_t ws_size,
                              hipStream_t stream)
{
  const float* X    = (const float*)d_in[0];
  const float* Cc   = (const float*)d_in[1];
  const float* Yh   = (const float*)d_in[2];
  const int*   EI   = (const int*)  d_in[3];
  const float* phiW = (const float*)d_in[4];  const float* phib = (const float*)d_in[5];
  const float* gcW  = (const float*)d_in[6];  const float* gcb  = (const float*)d_in[7];
  const float* ewl  = (const float*)d_in[8];
  const float* fuseW= (const float*)d_in[9];  const float* fuseb= (const float*)d_in[10];
  const float* o00W = (const float*)d_in[11]; const float* o00b = (const float*)d_in[12];
  const float* o10W = (const float*)d_in[13]; const float* o10b = (const float*)d_in[14];
  const float* o01W = (const float*)d_in[15]; const float* o01b = (const float*)d_in[16];
  const float* o11W = (const float*)d_in[17]; const float* o11b = (const float*)d_in[18];
  const float* ps1W = (const float*)d_in[19]; const float* ps1b = (const float*)d_in[20];
  const float* bng  = (const float*)d_in[21]; const float* bnb  = (const float*)d_in[22];
  const float* ps2W = (const float*)d_in[23]; const float* ps2b = (const float*)d_in[24];
  const float* Wih  = (const float*)d_in[25]; const float* Whh  = (const float*)d_in[26];
  const float* bih  = (const float*)d_in[27]; const float* bhh  = (const float*)d_in[28];
  float* out = (float*)d_out_v;

  char* wsb = (char*)d_ws;
  size_t off=0;
  auto alloc=[&](size_t bytes)->void*{
    void* p = wsb + off;
    off = (off + bytes + 255) & ~(size_t)255;
    return p;
  };
  uint*  degcnt= (uint*) alloc((size_t)TN*4);
  int*   cnt   = (int*)  alloc((size_t)TN*4);
  int*   offs  = (int*)  alloc(((size_t)TN+1)*4);
  float* dnv   = (float*)alloc((size_t)TN*4);
  float* invd  = (float*)alloc((size_t)TN*4);
  uint*  epack = (uint*) alloc((size_t)TE*4);
  ushort* rankb= (ushort*)alloc((size_t)TE*2);
  int*   parts = (int*)  alloc(4096);
  ushort* rep_all = (ushort*)alloc((size_t)TN*128*2);
  ushort* phiA = (ushort*)alloc((size_t)TN*256*2);   // -> zbf_all + cyh_all after pz
  ushort* xwb  = (ushort*)alloc((size_t)TN*128*2);
  ushort* pz   = (ushort*)alloc((size_t)TN*128*2);
  ushort* hbf0 = (ushort*)alloc((size_t)NN*256*2);   // bf16 h ping-pong
  ushort* hbf1 = (ushort*)alloc((size_t)NN*256*2);
  float*  hb   = (float*)alloc((size_t)NN*256*4);    // fp32 h (in-place safe)
  ushort* phiWt= (ushort*)alloc(256*128*2);
  ushort* gcWt = (ushort*)alloc((size_t)T_STEPS*128*256*2);
  ushort* WhT  = (ushort*)alloc(128*256*2);
  ushort* WrpT = (ushort*)alloc(128*384*2);
  ushort* Wgru = (ushort*)alloc((size_t)1024*448*2);
  float* bgru  = (float*)alloc(1024*4);
  ushort* wocT = (ushort*)alloc(256*128*2);
  ushort* ps1T = (ushort*)alloc(128*128*2);
  float* psc   = (float*)alloc(128*4);
  float* psb   = (float*)alloc(128*4);

  ushort* zbf     = phiA;                            // TN x 128 (alias)
  ushort* cyh     = phiA + (size_t)TN*128;           // TN x 64  (alias)

  hipMemsetAsync(degcnt, 0, (size_t)TN*4, stream);
  hipMemsetAsync(hb,   0, (size_t)NN*256*4, stream);
  hipMemsetAsync(hbf0, 0, (size_t)NN*256*2, stream);

  // --- single fused prep dispatch ---
  prep_k<<<3457,256,0,stream>>>(phiW, gcW, fuseW, ps1W, Wih, Whh, bih, bhh,
    o00W, o10W, ps1b, bng, bnb,
    phiWt, gcWt, WhT, WrpT, ps1T, Wgru, bgru, wocT, psc, psb);

  // --- CSR build ---
  count_k<<<(TE+255)/256,256,0,stream>>>(EI,ewl,degcnt,rankb);
  dinv_k<<<(TN+255)/256,256,0,stream>>>(degcnt,cnt,dnv,invd);
  scan1_k<<<(TN+1023)/1024,256,0,stream>>>(cnt,offs,parts,TN);
  scan2_k<<<1,256,0,stream>>>(parts,(TN+1023)/1024);
  scan3_k<<<(TN+255)/256,256,0,stream>>>(offs,parts,TN);
  fill_k<<<(TE+255)/256,256,0,stream>>>(EI,ewl,dnv,offs,rankb,epack);

  const size_t zoff  = (size_t)2*TN;
  const size_t psoff = zoff + (size_t)TN*128;
  const size_t hoff  = psoff + (size_t)TN*2;
  const Seg S0 = {nullptr,0,0,0};

  // --- batched recurrence-free work ---
  // phi_all = relu(X_t @ phi_W + b)  (fp32 A read + convert in staging, 512 thr)
  gemm_phi512<<<dim3(GX,1,8),512,0,stream>>>(
    X, phiWt, phib, phiA, (long)NN*256, NN);
  // xw_all = phi_all @ gc_W[t]
  gemm_bf<<<dim3(GX,1,8),256,0,stream>>>(
    Seg{phiA,256,(long)NN*256,256}, S0, S0, gcWt,256,(long)128*256, nullptr,0,
    nullptr,0,0, nullptr,0,0, xwb,128,(long)NN*128, NN,128);
  // rep_all (1D grid, t=bid&7)
  gather_k<<<(NN/4)*8,256,0,stream>>>(offs, epack, xwb, invd, gcb, rep_all);
  // pz_all = [rep_all | phi_all] @ [Wr;Wp]
  gemm_bf<<<dim3(GX,1,8),256,0,stream>>>(
    Seg{rep_all,128,(long)NN*128,128}, Seg{phiA,256,(long)NN*256,256}, S0,
    WrpT,384,0, nullptr,0,
    nullptr,0,0, nullptr,0,0, pz,128,(long)NN*128, NN,128);
  // cyh_all (overwrites upper phiA region; phi_all dead after pz)
  cyh_k<<<(int)(((long)TN*64+255)/256),256,0,stream>>>(cyh, Cc, Yh);

  // --- recurrent chain ---
  for (int t=0;t<T_STEPS;t++){
    const ushort* hbi = (t&1)? hbf1 : hbf0;
    ushort*       hbo = (t&1)? hbf0 : hbf1;
    float* hout = (t==T_STEPS-1)? (out+hoff) : hb;
    float* zt = out + zoff + (size_t)t*NN*128;
    ushort* zbt = zbf + (size_t)t*NN*128;
    // z = relu(h@Wh + pz_t + fuse_b) -> fp32 zt + bf16 zbf_t
    gemm_bf<<<dim3(GX,1,1),256,0,stream>>>(
      Seg{hbi,256,0,256}, S0, S0, WhT,256,0, fuseb,1,
      pz + (size_t)t*NN*128,128,0, zt,128,0, zbt,128,0, NN,128);
    // fused GRU -> h (fp32 in-place, bf16 ping-pong), 512 thr, 128x256 tiles
    gemm_gru512<<<dim3(GX,4),512,0,stream>>>(
      Seg{zbt,128,0,128}, Seg{cyh + (size_t)t*NN*64,64,0,64}, Seg{hbi,256,0,256},
      Wgru, bgru, hb, hout, hbo, NN);
  }

  // --- batched heads ---
  heads_k<<<dim3((NN+63)/64,1,8),256,0,stream>>>(
    zbf,(long)NN*128, wocT, o00b,o10b, o01W,o01b, o11W,o11b,
    out + TN, (long)NN,     // y0
    out, (long)NN, NN);     // y1
  ps_k<<<dim3(GX,1,8),256,0,stream>>>(
    zbf,(long)NN*128, ps1T, psc,psb, ps2W,ps2b,
    out+psoff, (long)NN*2, NN);

  (void)in_sizes; (void)n_in; (void)out_size; (void)ws_size;
}